// Round 4
// baseline (371.176 us; speedup 1.0000x reference)
//
#include <hip/hip_runtime.h>

#define TLEN  4096
#define NROWS 4096
#define RPB   32            // rows per block (owned by the scan wave)
#define K     32            // timesteps per chunk
#define NC    (TLEN / K)    // 128 chunks
#define SGSL  (16 * 64)     // sgin-coef slot: 16 tp-granules x 64 lanes (float4 units)
#define STP   33            // staging pitch (dwords): 32 steps + 1 pad -> bank = (lane+t)%32, 2-way max
#define STSL  (64 * STP)    // output-staging slot (floats): one 33-dword run per lane
#define UN    8             // exact-path unroll

__device__ __forceinline__ float fexp2(float x) { return __builtin_amdgcn_exp2f(x); }
__device__ __forceinline__ float frcp(float x)  { return __builtin_amdgcn_rcpf(x); }
__device__ __forceinline__ float sigz(float z)  { return frcp(1.0f + fexp2(z)); }

// Swap adjacent lanes (lane ^ 1): DPP quad_perm [1,0,3,2].
__device__ __forceinline__ float lane_swap1(float v) {
    int r = __builtin_amdgcn_update_dpp(0, __float_as_int(v), 0xB1, 0xF, 0xF, true);
    return __int_as_float(r);
}

// ---------------------------------------------------------------------------
// Round-4 structure. Measured law (r0-r3): wall = scan-stream-length x ~6.9cyc,
// invariant to ILP / co-residency; only stream shortening moves it.
//
//   wave 0 (scan): 12-slot step -- the Taylor sigma-update (6 ops + resync)
//     is replaced by the EXACT sigmoid (z,exp2,add,rcp = 4 ops; trans ops
//     cost ~1 slot, proven by r0's in-stream sgin), and the input term
//     collapses to one fma via helper-premultiplied coefs (a,b):
//       m   = fma(a, x, b)           // a = GnA*sgin, b = PA*sgin (helper)
//       t1v = fma(Gn1, x, P1); t2v = fma(Gn2, x, P2)
//       b2  = fma(sig, t1v, m); sc = DPP(sig); dx = fma(sc, t2v, b2)
//       x  += dx; st[lane*33 + t] = x
//       sig = rcp(1 + exp2(fma(c1s, x, c0s)))        // exact, no drift
//     Fast path is now EXACT -> all Taylor guards dropped; only the shared
//     mean/std structure (one sigma serves self+cross) is required.
//   wave 1 (helper): per chunk, 4 input sigmoids+premuls per float4 ->
//     sgbuf[(c+1)&1] (~240 slots), plus coalesced flush of st[(c-1)&1]
//     (~80 slots). ~320 slots/chunk rides under scan's ~380.
// ---------------------------------------------------------------------------
__device__ void run_fast(const float* __restrict__ inp, const float* __restrict__ prm,
                         float* __restrict__ out,
                         float4* __restrict__ sgbuf,  // [2][16 tp][64 lane] float4
                         float*  __restrict__ st) {   // [2][64 lane][STP]
    const int tid  = threadIdx.x;
    const int wid  = tid >> 6;          // 0 = scan wave, 1 = helper wave
    const int lane = tid & 63;
    const int R0   = blockIdx.x * RPB;
    const float L2E = 1.4426950408889634f;
    float2* __restrict__ out2 = (float2*)out;

    if (wid == 1) {
        // ---------------- helper wave ----------------
        const int r = lane & 31, h = lane >> 5;
        // input-dir constants: 'ax' (base 2) for x, 'by' (base 6) for y
        const float c1x = -prm[4] * L2E, c0x = prm[4] * prm[3] * L2E;
        const float c1y = -prm[8] * L2E, c0y = prm[8] * prm[7] * L2E;
        const float gAx = prm[2] / prm[0], PAx = gAx * prm[5], GnAx = -gAx;
        const float gAy = prm[6] / prm[1], PAy = gAy * prm[9], GnAy = -gAy;
        const float4* __restrict__ src = (const float4*)inp + (size_t)(R0 + r) * (TLEN / 2);

        auto produce = [&](int c) {   // coef pairs of chunk c -> sgbuf slot c&1
            float4* sl = sgbuf + ((c & 1) ? SGSL : 0);
            const int base = c * 16;
#pragma unroll
            for (int j = 0; j < 8; ++j) {
                const int tp = h * 8 + j;
                float4 v = src[base + tp];   // (a_t, b_t, a_t+1, b_t+1)
                float sx0 = sigz(__builtin_fmaf(c1x, v.x, c0x));
                float sy0 = sigz(__builtin_fmaf(c1y, v.y, c0y));
                float sx1 = sigz(__builtin_fmaf(c1x, v.z, c0x));
                float sy1 = sigz(__builtin_fmaf(c1y, v.w, c0y));
                float4 ox; ox.x = GnAx * sx0; ox.y = PAx * sx0;
                           ox.z = GnAx * sx1; ox.w = PAx * sx1;
                float4 oy; oy.x = GnAy * sy0; oy.y = PAy * sy0;
                           oy.z = GnAy * sy1; oy.w = PAy * sy1;
                sl[tp * 64 + 2 * r]     = ox;   // even lane (x) reads this
                sl[tp * 64 + 2 * r + 1] = oy;   // odd  lane (y) reads this
            }
        };
        auto flush = [&](int c) {     // st slot c&1 -> out, 256B coalesced runs
            const float* sl = st + ((c & 1) ? STSL : 0);
            const int col = lane & 31;
#pragma unroll
            for (int j = 0; j < 16; ++j) {
                int ro = 2 * j + (lane >> 5);
                float2 v;
                v.x = sl[(2 * ro)     * STP + col];
                v.y = sl[(2 * ro + 1) * STP + col];
                out2[(size_t)(R0 + ro) * TLEN + (size_t)c * K + col] = v;
            }
        };

        produce(0);
        __syncthreads();                       // slot 0 ready for scan
        for (int c = 0; c < NC; ++c) {
            if (c + 1 < NC) produce(c + 1);    // next chunk's coefs
            if (c >= 1)     flush(c - 1);      // previous chunk's outputs
            __syncthreads();
        }
        flush(NC - 1);                         // epilogue: last chunk's outputs
    } else {
        // ---------------- scan wave ----------------
        // Lane pair (2r, 2r+1) owns row r: even lane = x, odd = y.
        const int par = lane & 1;
        const int sfB = par ? 22 : 18, t2B = par ? 10 : 14;
        const float ic  = 1.0f / prm[par];
        const float g1  = prm[sfB] * ic, P1 = g1 * prm[sfB + 3], Gn1 = -g1; // self
        const float g2  = prm[t2B] * ic, P2 = g2 * prm[t2B + 3], Gn2 = -g2; // cross
        const float sdz = prm[sfB + 2];
        const float c1s = -sdz * L2E, c0s = sdz * prm[sfB + 1] * L2E;

        float x   = par ? 1.0f : 0.0f;
        float sig = sigz(__builtin_fmaf(c1s, x, c0s));

        auto step = [&](float a, float b, float* wp, int t) {
            float m   = __builtin_fmaf(a, x, b);      // input term (coefs premade)
            float t1v = __builtin_fmaf(Gn1, x, P1);
            float t2v = __builtin_fmaf(Gn2, x, P2);
            float b2  = __builtin_fmaf(sig, t1v, m);
            float sc  = lane_swap1(sig);              // partner's sigma
            float dx  = __builtin_fmaf(sc, t2v, b2);
            x = x + dx;
            wp[t] = x;                                // ds_write_b32, imm offset
            sig = sigz(__builtin_fmaf(c1s, x, c0s));  // exact sigma, 4 ops
        };

        __syncthreads();                       // sgbuf slot 0 ready
        for (int c = 0; c < NC; ++c) {
            const float4* lb = sgbuf + ((c & 1) ? SGSL : 0);
            float* wp = st + ((c & 1) ? STSL : 0) + lane * STP;
            float4 f0 = lb[lane];
            float4 f1 = lb[64 + lane];
#pragma unroll
            for (int tp = 0; tp < 16; ++tp) {
                float4 f = f0; f0 = f1;
                if (tp < 14) f1 = lb[(tp + 2) * 64 + lane];   // 2-granule lookahead
                step(f.x, f.y, wp, 2 * tp);
                step(f.z, f.w, wp, 2 * tp + 1);
            }
            __syncthreads();                   // hand slots to helper / get next
        }
    }
}

// ---------------------------------------------------------------------------
// Exact fallback for non-shared params (proven path; 128-thr blocks:
// blocks 0..63 cover all 8192 lanes, rest idle).
// ---------------------------------------------------------------------------
struct LaneConst {
    float c1_in, c0_in, c1_sf, c0_sf, c1_ot, c0_ot;
    float gS_in, gS_cr, gS_sf, gP_in, gP_cr, gP_sf;
};

__device__ __forceinline__ float do_step_exact(float s, float pre_in, const LaneConst& k) {
    float sig_in = sigz(__builtin_fmaf(k.c1_in, pre_in, k.c0_in));
    float sig_sf = sigz(__builtin_fmaf(k.c1_sf, s, k.c0_sf));
    float sig_ot = sigz(__builtin_fmaf(k.c1_ot, s, k.c0_ot));
    float sig_cr = lane_swap1(sig_ot);
    float S = __builtin_fmaf(k.gS_in, sig_in, __builtin_fmaf(k.gS_cr, sig_cr, k.gS_sf * sig_sf));
    float P = __builtin_fmaf(k.gP_in, sig_in, __builtin_fmaf(k.gP_cr, sig_cr, k.gP_sf * sig_sf));
    return s + __builtin_fmaf(S, -s, P);
}

__device__ void run_exact(const float* __restrict__ inp, const float* __restrict__ prm,
                          float* __restrict__ out) {
    const int tid = blockIdx.x * 128 + threadIdx.x;
    const int row = tid >> 1;
    if (row >= NROWS) return;
    const int par = tid & 1;
    const float L2E = 1.4426950408889634f;
    const int inB = par ? 6 : 2, sfB = par ? 22 : 18, otB = par ? 14 : 10, crB = par ? 10 : 14;
    const float invc = 1.0f / prm[par];
    LaneConst k;
    float sd = prm[inB + 2], mn = prm[inB + 1];
    k.c1_in = -sd * L2E; k.c0_in = sd * mn * L2E;
    sd = prm[sfB + 2]; mn = prm[sfB + 1];
    k.c1_sf = -sd * L2E; k.c0_sf = sd * mn * L2E;
    sd = prm[otB + 2]; mn = prm[otB + 1];
    k.c1_ot = -sd * L2E; k.c0_ot = sd * mn * L2E;
    k.gS_in = prm[inB] * invc; k.gP_in = k.gS_in * prm[inB + 3];
    k.gS_sf = prm[sfB] * invc; k.gP_sf = k.gS_sf * prm[sfB + 3];
    k.gS_cr = prm[crB] * invc; k.gP_cr = k.gS_cr * prm[crB + 3];

    const float4* __restrict__ src = (const float4*)inp + (size_t)row * (TLEN / 2);
    float* __restrict__ dst = out + (size_t)row * (TLEN * 2) + par;
    float s = par ? 1.0f : 0.0f;

    float4 cur[UN], nxt[UN];
#pragma unroll
    for (int j = 0; j < UN; ++j) cur[j] = src[j];
    const int NIT = TLEN / (2 * UN);
    for (int it = 0; it < NIT; ++it) {
        if (it + 1 < NIT) {
#pragma unroll
            for (int j = 0; j < UN; ++j) nxt[j] = src[(it + 1) * UN + j];
        }
        float* dptr = dst + it * (UN * 4);
#pragma unroll
        for (int j = 0; j < UN; ++j) {
            float4 f = cur[j];
            s = do_step_exact(s, par ? f.y : f.x, k);
            dptr[j * 4] = s;
            s = do_step_exact(s, par ? f.w : f.z, k);
            dptr[j * 4 + 2] = s;
        }
#pragma unroll
        for (int j = 0; j < UN; ++j) cur[j] = nxt[j];
    }
}

__global__ __launch_bounds__(128, 1)
void memcell_scan(const float* __restrict__ inp, const float* __restrict__ prm,
                  float* __restrict__ out) {
    __shared__ float4 sgbuf[2 * SGSL];   // 32 KB coef double-buffer
    __shared__ float  st[2 * STSL];      // 16.5 KB output staging double-buffer

    // Fast-path guard: ONLY the shared mean/std structure is needed now
    // (xx==xy and yy==yx in mean,std), so one sigma per lane serves both the
    // self term and the partner's cross term. The fast path computes that
    // sigma EXACTLY each step -> no Taylor validity conditions remain.
    const bool shared = (prm[11] == prm[19]) && (prm[12] == prm[20]) &&
                        (prm[15] == prm[23]) && (prm[16] == prm[24]);
    if (shared) {
        run_fast(inp, prm, out, sgbuf, st);
    } else {
        run_exact(inp, prm, out);
    }
}

extern "C" void kernel_launch(void* const* d_in, const int* in_sizes, int n_in,
                              void* d_out, int out_size, void* d_ws, size_t ws_size,
                              hipStream_t stream) {
    (void)in_sizes; (void)n_in; (void)d_ws; (void)ws_size; (void)out_size;
    const float* inp = (const float*)d_in[0];
    const float* prm = (const float*)d_in[1];
    float* out = (float*)d_out;
    memcell_scan<<<dim3(NROWS / RPB), dim3(128), 0, stream>>>(inp, prm, out);
}